// Round 11
// baseline (266.345 us; speedup 1.0000x reference)
//
#include <hip/hip_runtime.h>

#define NN 50000
#define EE 800000
#define ET (EE + NN)
#define NCH ((NN + 255) / 256)   // 196 chunks of 256 nodes

typedef unsigned short ushort_t;
using bf16x8 = __attribute__((ext_vector_type(8))) short;
using f32x4  = __attribute__((ext_vector_type(4))) float;

__device__ __forceinline__ float bf2f(ushort_t u) {
    return __uint_as_float(((unsigned int)u) << 16);
}
__device__ __forceinline__ ushort_t f2bf(float f) {
    unsigned int u = __float_as_uint(f);
    u += 0x7fffu + ((u >> 16) & 1u);
    return (ushort_t)(u >> 16);
}
__device__ __forceinline__ float lrelu(float e) {
    return fmaxf(e, 0.f) + 0.2f * fminf(e, 0.f);
}
// load float input that may be fp32 or bf16, per sniffed flag
__device__ __forceinline__ float ldf(const void* p, int i, bool f32) {
    return f32 ? ((const float*)p)[i] : bf2f(((const ushort_t*)p)[i]);
}

// ---------------- dtype sniffer: flags[0]=float inputs are fp32, flags[1]=edge_index is int64 ----------------
__global__ __launch_bounds__(256) void sniff_kernel(const unsigned int* xw, const int* eiw, int* flags) {
    __shared__ int cnt0, cnt1;
    int t = threadIdx.x;
    if (t == 0) { cnt0 = 0; cnt1 = 0; }
    __syncthreads();
    float v = __uint_as_float(xw[t]);
    float a = fabsf(v);
    if ((a > 1e-6f && a < 1e6f) || v == 0.f) atomicAdd(&cnt0, 1);
    if (eiw[2 * t + 1] != 0) atomicAdd(&cnt1, 1);
    __syncthreads();
    if (t == 0) {
        flags[0] = (cnt0 >= 192) ? 1 : 0;
        flags[1] = (cnt1 <= 16) ? 1 : 0;
    }
}

// ---------------- CSR build ----------------
__device__ __forceinline__ void edge_sd(const int* ei, int i, bool i64, int& s, int& d) {
    if (i < EE) {
        if (i64) { s = ei[2 * i]; d = ei[2 * (EE + i)]; }
        else     { s = ei[i];     d = ei[EE + i]; }
    } else {
        s = d = i - EE;
    }
}

// degree + rank in one pass; 8 XCD-local histogram slices (g = blockIdx&7 tracks the
// hardware's round-robin blockIdx->XCD map) so atomic lines stay in one L2.
__global__ __launch_bounds__(256) void degree_rank_kernel(const int* ei, int* deg8, int* rank, const int* flags) {
    int i = blockIdx.x * 256 + threadIdx.x;
    if (i >= ET) return;
    bool i64 = flags[1] != 0;
    int g = blockIdx.x & 7;
    int s, d;
    edge_sd(ei, i, i64, s, d);
    rank[i] = atomicAdd(&deg8[(size_t)g * NN + d], 1);
}

// ---- 3-phase parallel scan over 196 chunks of 256 nodes ----
__global__ __launch_bounds__(256) void scanA_kernel(const int* __restrict__ deg8, int* __restrict__ chunksum) {
    __shared__ int wsum[4];
    int t = threadIdx.x;
    int node = blockIdx.x * 256 + t;
    int v = 0;
    if (node < NN) {
        #pragma unroll
        for (int g = 0; g < 8; ++g) v += deg8[(size_t)g * NN + node];
    }
    int lane = t & 63, wid = t >> 6;
    #pragma unroll
    for (int off = 1; off < 64; off <<= 1) v += __shfl_xor(v, off);
    if (lane == 0) wsum[wid] = v;
    __syncthreads();
    if (t == 0) chunksum[blockIdx.x] = wsum[0] + wsum[1] + wsum[2] + wsum[3];
}

__global__ __launch_bounds__(256) void scanB_kernel(const int* __restrict__ chunksum, int* __restrict__ chunkoff,
                                                    int* __restrict__ rowptr) {
    __shared__ int wsum[4];
    int t = threadIdx.x;
    int lane = t & 63, wid = t >> 6;
    int v = (t < NCH) ? chunksum[t] : 0;
    int x = v;
    #pragma unroll
    for (int off = 1; off < 64; off <<= 1) {
        int y = __shfl_up(x, off);
        if (lane >= off) x += y;
    }
    if (lane == 63) wsum[wid] = x;
    __syncthreads();
    if (t < 4) {
        int s = wsum[t];
        #pragma unroll
        for (int off = 1; off < 4; off <<= 1) {
            int y = __shfl_up(s, off);
            if (t >= off) s += y;
        }
        wsum[t] = s;
    }
    __syncthreads();
    int incl = x + ((wid > 0) ? wsum[wid - 1] : 0);
    if (t < NCH) chunkoff[t] = incl - v;
    if (t == 255) rowptr[NN] = wsum[3];
}

__global__ __launch_bounds__(256) void scanC_kernel(int* __restrict__ deg8, int* __restrict__ rowptr,
                                                    const int* __restrict__ chunkoff) {
    __shared__ int wsum[4];
    int t = threadIdx.x;
    int node = blockIdx.x * 256 + t;
    int dv[8];
    int v = 0;
    if (node < NN) {
        #pragma unroll
        for (int g = 0; g < 8; ++g) {
            dv[g] = deg8[(size_t)g * NN + node];
            v += dv[g];
        }
    }
    int lane = t & 63, wid = t >> 6;
    int x = v;
    #pragma unroll
    for (int off = 1; off < 64; off <<= 1) {
        int y = __shfl_up(x, off);
        if (lane >= off) x += y;
    }
    if (lane == 63) wsum[wid] = x;
    __syncthreads();
    if (t < 4) {
        int s = wsum[t];
        #pragma unroll
        for (int off = 1; off < 4; off <<= 1) {
            int y = __shfl_up(s, off);
            if (t >= off) s += y;
        }
        wsum[t] = s;
    }
    __syncthreads();
    int excl = x - v + ((wid > 0) ? wsum[wid - 1] : 0);
    if (node < NN) {
        int run = chunkoff[blockIdx.x] + excl;
        rowptr[node] = run;
        #pragma unroll
        for (int g = 0; g < 8; ++g) {
            deg8[(size_t)g * NN + node] = run;
            run += dv[g];
        }
    }
}

// atomic-free fill: pos = deg8off[g][d] + rank[i] (same blockIdx->g map as degree_rank)
__global__ __launch_bounds__(256) void fill_kernel(const int* ei, const int* deg8off, const int* rank,
                                                   int* col, const int* flags) {
    int i = blockIdx.x * 256 + threadIdx.x;
    if (i >= ET) return;
    bool i64 = flags[1] != 0;
    int g = blockIdx.x & 7;
    int s, d;
    edge_sd(ei, i, i64, s, d);
    col[deg8off[(size_t)g * NN + d] + rank[i]] = s;
}

// ---------------- W pre-transpose to bf16: Wt[nc][k] (k-major rows of 128) ----------------
__global__ __launch_bounds__(256) void wtprep_kernel(const void* W1v, const void* W2v,
                                                     ushort_t* Wt1, ushort_t* Wt2, const int* flags) {
    bool f32 = flags[0] != 0;
    int i = blockIdx.x * 256 + threadIdx.x;
    if (i < 128 * 128) {                       // W1[k][nc], k=i>>7, nc=i&127 (coalesced read)
        int k = i >> 7, nc = i & 127;
        ushort_t v = f32 ? f2bf(((const float*)W1v)[i]) : ((const ushort_t*)W1v)[i];
        Wt1[nc * 128 + k] = v;
    }
    int j = i - 128 * 128;
    if (j >= 0 && j < 128 * 64) {              // W2[k][nc], k=j>>6, nc=j&63
        int k = j >> 6, nc = j & 63;
        ushort_t v = f32 ? f2bf(((const float*)W2v)[j]) : ((const ushort_t*)W2v)[j];
        Wt2[nc * 128 + k] = v;
    }
}

// ---------------- MFMA GEMM, no LDS: A global->VGPR streamed, B (Wt) global->VGPR L2-resident ----------------
// out_bf16[n, NCOL] = A[n,128] @ W[128,NCOL]; asrc/adst per head fused.
// MFMA 16x16x32_bf16: A[m=lane&15][k=quad*8+j]; B[k][n=lane&15]; C/D col=lane&15, row=quad*4+reg.
template <bool AEXT, int NCOL, int NH>
__global__ __launch_bounds__(256) void mgemm_kernel(const void* Av, const ushort_t* __restrict__ Wt,
                                                    const void* a_src, const void* a_dst,
                                                    ushort_t* outb, float* asrc, float* adst,
                                                    int n, const int* flags) {
    constexpr int K = 128;
    constexpr int NCT = NCOL / 16;            // col tiles (8 or 4)
    bool f32 = flags[0] != 0;
    bool af32 = AEXT && f32;                  // internal A (hmid) is always bf16
    int t = threadIdx.x;
    int lane = t & 63, wid = t >> 6;
    int m = lane & 15, quad = lane >> 4;
    int rbase = blockIdx.x * 64 + wid * 16;
    int row = rbase + m;
    bool rok = row < n;

    // ---- A fragments: all 4 kk chunks loaded up front (max MLP) ----
    bf16x8 af[4];
    if (rok) {
        if (!af32) {
            const ushort_t* ap = (const ushort_t*)Av + (size_t)row * K + quad * 8;
            #pragma unroll
            for (int kk = 0; kk < 4; ++kk) af[kk] = *(const bf16x8*)(ap + kk * 32);
        } else {
            const float* ap = (const float*)Av + (size_t)row * K + quad * 8;
            #pragma unroll
            for (int kk = 0; kk < 4; ++kk) {
                float4 q0 = *(const float4*)(ap + kk * 32);
                float4 q1 = *(const float4*)(ap + kk * 32 + 4);
                bf16x8 v;
                v[0] = (short)f2bf(q0.x); v[1] = (short)f2bf(q0.y);
                v[2] = (short)f2bf(q0.z); v[3] = (short)f2bf(q0.w);
                v[4] = (short)f2bf(q1.x); v[5] = (short)f2bf(q1.y);
                v[6] = (short)f2bf(q1.z); v[7] = (short)f2bf(q1.w);
                af[kk] = v;
            }
        }
    } else {
        #pragma unroll
        for (int kk = 0; kk < 4; ++kk) af[kk] = (bf16x8){0, 0, 0, 0, 0, 0, 0, 0};
    }

    f32x4 acc[NCT];
    #pragma unroll
    for (int c = 0; c < NCT; ++c) acc[c] = (f32x4){0.f, 0.f, 0.f, 0.f};

    // B fragments: Wt[(c*16+m)][kk*32 + quad*8 ..+8] — wave covers contiguous 4KB, L1/L2-hit
    const ushort_t* wp = Wt + (size_t)m * K + quad * 8;
    #pragma unroll
    for (int c = 0; c < NCT; ++c) {
        const ushort_t* wc = wp + (size_t)c * 16 * K;
        #pragma unroll
        for (int kk = 0; kk < 4; ++kk) {
            bf16x8 bf = *(const bf16x8*)(wc + kk * 32);
            acc[c] = __builtin_amdgcn_mfma_f32_16x16x32_bf16(af[kk], bf, acc[c], 0, 0, 0);
        }
    }

    // ---- epilogue 1: bf16 store of h tile (C layout: row=quad*4+r, col=c*16+m) ----
    int orow0 = rbase + quad * 4;
    #pragma unroll
    for (int c = 0; c < NCT; ++c) {
        #pragma unroll
        for (int r = 0; r < 4; ++r) {
            int orow = orow0 + r;
            if (orow < n) outb[(size_t)orow * NCOL + c * 16 + m] = f2bf(acc[c][r]);
        }
    }

    // ---- epilogue 2: fused alpha dot products ----
    if (NH == 8) {
        #pragma unroll
        for (int c = 0; c < NCT; ++c) {       // c == head
            float as = ldf(a_src, c * 16 + m, f32);
            float ad = ldf(a_dst, c * 16 + m, f32);
            float ps[4], pd[4];
            #pragma unroll
            for (int r = 0; r < 4; ++r) { ps[r] = acc[c][r] * as; pd[r] = acc[c][r] * ad; }
            #pragma unroll
            for (int stp = 1; stp < 16; stp <<= 1) {
                #pragma unroll
                for (int r = 0; r < 4; ++r) {
                    ps[r] += __shfl_xor(ps[r], stp);
                    pd[r] += __shfl_xor(pd[r], stp);
                }
            }
            if (m == 0) {
                #pragma unroll
                for (int r = 0; r < 4; ++r) {
                    int orow = orow0 + r;
                    if (orow < n) {
                        asrc[(size_t)orow * 8 + c] = ps[r];
                        adst[(size_t)orow * 8 + c] = pd[r];
                    }
                }
            }
        }
    } else {
        float ps[4] = {0.f, 0.f, 0.f, 0.f}, pd[4] = {0.f, 0.f, 0.f, 0.f};
        #pragma unroll
        for (int c = 0; c < NCT; ++c) {
            float as = ldf(a_src, c * 16 + m, f32);
            float ad = ldf(a_dst, c * 16 + m, f32);
            #pragma unroll
            for (int r = 0; r < 4; ++r) {
                ps[r] = fmaf(acc[c][r], as, ps[r]);
                pd[r] = fmaf(acc[c][r], ad, pd[r]);
            }
        }
        #pragma unroll
        for (int stp = 1; stp < 16; stp <<= 1) {
            #pragma unroll
            for (int r = 0; r < 4; ++r) {
                ps[r] += __shfl_xor(ps[r], stp);
                pd[r] += __shfl_xor(pd[r], stp);
            }
        }
        if (m == 0) {
            #pragma unroll
            for (int r = 0; r < 4; ++r) {
                int orow = orow0 + r;
                if (orow < n) { asrc[orow] = ps[r]; adst[orow] = pd[r]; }
            }
        }
    }
}

// ---------------- layer-1 aggregation: one wave per dst node, paired-edge phase 2 ----------------
// Phase 1 (lanes=edges): coalesced col load; 8 head-exps -> LDS (zero-padded past cnt).
// Phase 2: TWO edges per iteration — half-wave per edge, each lane covers 4 dims via one 8B load.
// Final shfl_xor(...,32) combines the two half-wave partials.
__global__ __launch_bounds__(256) void agg1_kernel(const int* __restrict__ rowptr, const int* __restrict__ col,
                                                   const ushort_t* __restrict__ h1b,
                                                   const float* __restrict__ asrc, const float* __restrict__ adst,
                                                   const void* b1, ushort_t* __restrict__ hmidb, const int* flags) {
    __shared__ float wle[4][8 * 72];
    __shared__ int loff[4][64];
    bool f32 = flags[0] != 0;
    int lane = threadIdx.x & 63, wid = threadIdx.x >> 6;
    int d = blockIdx.x * 4 + wid;       // NN % 4 == 0: every wave has a valid node
    int start = rowptr[d], end = rowptr[d + 1];
    int sub = lane >> 5;                // which edge of the pair
    int l = lane & 31;                  // dim group: dims 4l..4l+3
    int h2x = l >> 2;                   // head of those dims
    const float4* dp = (const float4*)(adst + (size_t)d * 8);
    float4 ad0 = dp[0], ad1 = dp[1];    // wave-uniform broadcast load
    const char* hb = (const char*)h1b + l * 8;   // lane byte offset within row
    float acc0 = 0.f, acc1 = 0.f, acc2 = 0.f, acc3 = 0.f, ssum = 0.f;
    for (int chunk = start; chunk < end; chunk += 64) {
        int cnt = min(64, end - chunk);
        bool valid = lane < cnt;
        int c = valid ? col[chunk + lane] : 0;
        loff[wid][lane] = c << 8;       // byte offset of 256B h1b row (0 for pad)
        {
            const float4* ap = (const float4*)(asrc + (size_t)c * 8);
            float4 s0 = ap[0], s1 = ap[1];
            float z = valid ? 1.f : 0.f;
            wle[wid][0 * 72 + lane] = z * __expf(lrelu(s0.x + ad0.x));
            wle[wid][1 * 72 + lane] = z * __expf(lrelu(s0.y + ad0.y));
            wle[wid][2 * 72 + lane] = z * __expf(lrelu(s0.z + ad0.z));
            wle[wid][3 * 72 + lane] = z * __expf(lrelu(s0.w + ad0.w));
            wle[wid][4 * 72 + lane] = z * __expf(lrelu(s1.x + ad1.x));
            wle[wid][5 * 72 + lane] = z * __expf(lrelu(s1.y + ad1.y));
            wle[wid][6 * 72 + lane] = z * __expf(lrelu(s1.z + ad1.z));
            wle[wid][7 * 72 + lane] = z * __expf(lrelu(s1.w + ad1.w));
        }
        int cntR = (cnt + 1) & ~1;      // padded entries contribute ex=0
        #pragma unroll 2
        for (int j = 0; j < cntR; j += 2) {
            int off = loff[wid][j + sub];
            float ex = wle[wid][h2x * 72 + j + sub];
            uint2 hv = *(const uint2*)(hb + off);
            ssum += ex;
            acc0 = fmaf(ex, __uint_as_float(hv.x << 16), acc0);
            acc1 = fmaf(ex, __uint_as_float(hv.x & 0xffff0000u), acc1);
            acc2 = fmaf(ex, __uint_as_float(hv.y << 16), acc2);
            acc3 = fmaf(ex, __uint_as_float(hv.y & 0xffff0000u), acc3);
        }
    }
    // combine the two half-wave partials
    ssum += __shfl_xor(ssum, 32);
    acc0 += __shfl_xor(acc0, 32);
    acc1 += __shfl_xor(acc1, 32);
    acc2 += __shfl_xor(acc2, 32);
    acc3 += __shfl_xor(acc3, 32);
    float inv = 1.f / (ssum + 1e-16f);
    float o0 = fmaf(acc0, inv, ldf(b1, l * 4 + 0, f32));
    float o1 = fmaf(acc1, inv, ldf(b1, l * 4 + 1, f32));
    float o2 = fmaf(acc2, inv, ldf(b1, l * 4 + 2, f32));
    float o3 = fmaf(acc3, inv, ldf(b1, l * 4 + 3, f32));
    o0 = (o0 > 0.f) ? o0 : (__expf(o0) - 1.f);   // ELU
    o1 = (o1 > 0.f) ? o1 : (__expf(o1) - 1.f);
    o2 = (o2 > 0.f) ? o2 : (__expf(o2) - 1.f);
    o3 = (o3 > 0.f) ? o3 : (__expf(o3) - 1.f);
    if (sub == 0) {
        uint2 pk;
        pk.x = ((unsigned int)f2bf(o1) << 16) | (unsigned int)f2bf(o0);
        pk.y = ((unsigned int)f2bf(o3) << 16) | (unsigned int)f2bf(o2);
        *(uint2*)(hmidb + (size_t)d * 128 + l * 4) = pk;
    }
}

// ---------------- layer-2 aggregation: paired-edge phase 2 + log_softmax; fp32 output ----------------
__global__ __launch_bounds__(256) void agg2_kernel(const int* __restrict__ rowptr, const int* __restrict__ col,
                                                   const ushort_t* __restrict__ h2b,
                                                   const float* __restrict__ asrc, const float* __restrict__ adst,
                                                   const void* b2, float* __restrict__ out, const int* flags) {
    __shared__ float wle[4][64];
    __shared__ int loff[4][64];
    bool f32 = flags[0] != 0;
    int lane = threadIdx.x & 63, wid = threadIdx.x >> 6;
    int d = blockIdx.x * 4 + wid;
    int start = rowptr[d], end = rowptr[d + 1];
    int sub = lane >> 5;
    int l = lane & 31;                  // dims 2l, 2l+1
    float ad = adst[d];
    const char* hb = (const char*)h2b + l * 4;
    float acc0 = 0.f, acc1 = 0.f, ssum = 0.f;
    for (int chunk = start; chunk < end; chunk += 64) {
        int cnt = min(64, end - chunk);
        bool valid = lane < cnt;
        int c = valid ? col[chunk + lane] : 0;
        loff[wid][lane] = c << 7;       // byte offset of 128B h2b row
        wle[wid][lane] = valid ? __expf(lrelu(asrc[c] + ad)) : 0.f;
        int cntR = (cnt + 1) & ~1;
        #pragma unroll 2
        for (int j = 0; j < cntR; j += 2) {
            int off = loff[wid][j + sub];
            float ex = wle[wid][j + sub];
            unsigned int hv = *(const unsigned int*)(hb + off);
            ssum += ex;
            acc0 = fmaf(ex, __uint_as_float(hv << 16), acc0);
            acc1 = fmaf(ex, __uint_as_float(hv & 0xffff0000u), acc1);
        }
    }
    ssum += __shfl_xor(ssum, 32);
    acc0 += __shfl_xor(acc0, 32);
    acc1 += __shfl_xor(acc1, 32);
    float inv = 1.f / (ssum + 1e-16f);
    float o0 = fmaf(acc0, inv, ldf(b2, 2 * l + 0, f32));
    float o1 = fmaf(acc1, inv, ldf(b2, 2 * l + 1, f32));
    // log_softmax over 64 classes (held as 2/lane, duplicated across half-waves -> reduce within 32)
    float mm = fmaxf(o0, o1);
    #pragma unroll
    for (int off = 1; off < 32; off <<= 1) mm = fmaxf(mm, __shfl_xor(mm, off));
    float ts = __expf(o0 - mm) + __expf(o1 - mm);
    #pragma unroll
    for (int off = 1; off < 32; off <<= 1) ts += __shfl_xor(ts, off);
    float lt = __logf(ts);
    if (sub == 0) {
        *(float2*)(out + (size_t)d * 64 + 2 * l) = make_float2(o0, o1);
        *(float2*)(out + (size_t)NN * 64 + (size_t)d * 64 + 2 * l) = make_float2(o0 - mm - lt, o1 - mm - lt);
    }
}

extern "C" void kernel_launch(void* const* d_in, const int* in_sizes, int n_in,
                              void* d_out, int out_size, void* d_ws, size_t ws_size,
                              hipStream_t stream) {
    const void* x   = d_in[0];
    const int*  ei  = (const int*)d_in[1];
    const void* W1  = d_in[2];
    const void* as1 = d_in[3];
    const void* ad1 = d_in[4];
    const void* b1  = d_in[5];
    const void* W2  = d_in[6];
    const void* as2 = d_in[7];
    const void* ad2 = d_in[8];
    const void* b2  = d_in[9];
    float* out = (float*)d_out;

    char* w = (char*)d_ws;
    auto alloc = [&](size_t bytes) {
        void* p = (void*)w;
        w += (bytes + 255) & ~(size_t)255;
        return p;
    };
    int* flags    = (int*)alloc(256);
    int* deg8     = (int*)alloc((size_t)8 * NN * 4);
    int* rowptr   = (int*)alloc((size_t)(NN + 1) * 4);
    int* chunksum = (int*)alloc((size_t)NCH * 4);
    int* chunkoff = (int*)alloc((size_t)NCH * 4);
    int* rank     = (int*)alloc((size_t)ET * 4);
    int* colx     = (int*)alloc((size_t)ET * 4);
    ushort_t* Wt1 = (ushort_t*)alloc((size_t)128 * 128 * 2);
    ushort_t* Wt2 = (ushort_t*)alloc((size_t)64 * 128 * 2);
    ushort_t* h1b = (ushort_t*)alloc((size_t)NN * 128 * 2);
    float* asrc1  = (float*)alloc((size_t)NN * 8 * 4);
    float* adst1  = (float*)alloc((size_t)NN * 8 * 4);
    ushort_t* hmidb = (ushort_t*)alloc((size_t)NN * 128 * 2);
    ushort_t* h2b = (ushort_t*)alloc((size_t)NN * 64 * 2);
    float* asrc2  = (float*)alloc((size_t)NN * 4);
    float* adst2  = (float*)alloc((size_t)NN * 4);

    sniff_kernel<<<1, 256, 0, stream>>>((const unsigned int*)x, ei, flags);

    hipMemsetAsync(deg8, 0, (size_t)8 * NN * 4, stream);
    degree_rank_kernel<<<(ET + 255) / 256, 256, 0, stream>>>(ei, deg8, rank, flags);
    scanA_kernel<<<NCH, 256, 0, stream>>>(deg8, chunksum);
    scanB_kernel<<<1, 256, 0, stream>>>(chunksum, chunkoff, rowptr);
    scanC_kernel<<<NCH, 256, 0, stream>>>(deg8, rowptr, chunkoff);
    fill_kernel<<<(ET + 255) / 256, 256, 0, stream>>>(ei, deg8, rank, colx, flags);
    wtprep_kernel<<<(128 * 128 + 128 * 64 + 255) / 256, 256, 0, stream>>>(W1, W2, Wt1, Wt2, flags);

    int gblocks = (NN + 63) / 64;
    mgemm_kernel<true, 128, 8><<<gblocks, 256, 0, stream>>>(x, Wt1, as1, ad1, h1b, asrc1, adst1, NN, flags);
    agg1_kernel<<<NN / 4, 256, 0, stream>>>(rowptr, colx, h1b, asrc1, adst1, b1, hmidb, flags);

    mgemm_kernel<false, 64, 1><<<gblocks, 256, 0, stream>>>((const void*)hmidb, Wt2, as2, ad2, h2b, asrc2, adst2, NN, flags);
    agg2_kernel<<<NN / 4, 256, 0, stream>>>(rowptr, colx, h2b, asrc2, adst2, b2, out, flags);
}